// Round 1
// baseline (269.546 us; speedup 1.0000x reference)
//
#include <hip/hip_runtime.h>
#include <stdint.h>

#define BH 32
#define LSEQ 4096
#define DDIM 128
#define BS 32
#define NBLK 128
#define CHUNKS 16
#define BLK_PER_CHUNK 8
#define STATE_SZ (DDIM*DDIM + DDIM)   // 16512 floats per (bh, chunk)

typedef __attribute__((ext_vector_type(8))) short bf16x8;
typedef __attribute__((ext_vector_type(4))) float f32x4;

__device__ inline uint16_t f2bf(float f) {
    uint32_t x = __builtin_bit_cast(uint32_t, f);
    x += 0x7fffu + ((x >> 16) & 1u);
    return (uint16_t)(x >> 16);
}
__device__ inline float bflo(uint32_t w){ return __builtin_bit_cast(float, w << 16); }
__device__ inline float bfhi(uint32_t w){ return __builtin_bit_cast(float, w & 0xffff0000u); }

// phi(x) = clip(elu(x*s+b)+1, 0, 10) = (y>0) ? min(y+1,10) : exp(y)
__device__ inline float phi_f(float x, float s, float b) {
    float y = fmaf(x, s, b);
    float pos = fminf(y + 1.0f, 10.0f);
    float neg = __expf(y);
    return (y > 0.0f) ? pos : neg;
}

// LDS byte offsets (total 62080 B):
//   [0,34816)       : S_bfT [128][136] bf16 (phase2); overlays pk_bf [32][136] @0, v_bf [32][136] @8704
//   [34816,45056)   : pkT [128][40] bf16 ; overlays pq_bf [32][136] (phase2, after update MFMAs)
//   [45056,55296)   : vT  [128][40] bf16
//   [55296,55808)   : Zl   [128] f32
//   [55808,59904)   : Zpart[8][128] f32
//   [59904,61952)   : den_part [32][16] f32
//   [61952,62080)   : inv_den [32] f32
#define SMEM_BYTES 62080

template<bool PHASE2>
__global__ __launch_bounds__(512, 4) void la_phase(
    const float* __restrict__ Q, const float* __restrict__ K,
    const float* __restrict__ V, const float* __restrict__ scale,
    const float* __restrict__ bias, float* __restrict__ states,
    float* __restrict__ out)
{
    extern __shared__ char smem[];
    uint16_t* S_bfT  = (uint16_t*)smem;
    uint16_t* pk_bf  = (uint16_t*)smem;
    uint16_t* v_bf   = (uint16_t*)(smem + 8704);
    uint16_t* pkT    = (uint16_t*)(smem + 34816);
    uint16_t* pq_bf  = pkT;
    uint16_t* vT     = (uint16_t*)(smem + 45056);
    float* Zl        = (float*)(smem + 55296);
    float* Zpart     = Zl + 128;
    float* den_part  = Zpart + 8*128;
    float* inv_den   = den_part + 32*16;

    const int tid  = threadIdx.x;
    const int bid  = blockIdx.x;
    const int bh   = bid >> 4;        // / CHUNKS
    const int ch   = bid & 15;
    const int lane = tid & 63;
    const int wv   = tid >> 6;        // wave 0..7, owns e in [16wv,16wv+16)
    const int i15  = lane & 15;
    const int q4   = lane >> 4;

    const size_t base = (size_t)bh * LSEQ * DDIM;
    const int h = bh & 15;

    // staging assignment: row sr (0..31), cols [sc, sc+8)
    const int sr = tid >> 4;
    const int sc = (tid & 15) * 8;

    float sreg[8], breg[8];
    #pragma unroll
    for (int j = 0; j < 8; ++j) {
        sreg[j] = scale[h*DDIM + sc + j];
        breg[j] = bias[h*DDIM + sc + j];
    }

    f32x4 accS[8];
    float* stbase = states + (size_t)(bh*CHUNKS + ch) * STATE_SZ;

    if (PHASE2) {
        #pragma unroll
        for (int mt = 0; mt < 8; ++mt) {
            #pragma unroll
            for (int r = 0; r < 4; ++r) {
                int d = 16*mt + 4*q4 + r;
                accS[mt][r] = stbase[d*DDIM + 16*wv + i15];
            }
        }
        if (tid < 128) Zl[tid] = stbase[DDIM*DDIM + tid];
    } else {
        #pragma unroll
        for (int mt = 0; mt < 8; ++mt) accS[mt] = (f32x4){0.f,0.f,0.f,0.f};
        if (tid < 128) Zl[tid] = 0.f;
    }
    __syncthreads();

    for (int s = 0; s < BLK_PER_CHUNK; ++s) {
        const int blk = ch * BLK_PER_CHUNK + s;
        const size_t rowoff = base + (size_t)(blk*BS + sr) * DDIM + sc;

        // ---- 1. stage phi(K) and bf16(V) into LDS (b128 writes)
        {
            const float4 k0 = *(const float4*)(K + rowoff);
            const float4 k1 = *(const float4*)(K + rowoff + 4);
            const float4 v0 = *(const float4*)(V + rowoff);
            const float4 v1 = *(const float4*)(V + rowoff + 4);
            float kp[8] = {k0.x,k0.y,k0.z,k0.w,k1.x,k1.y,k1.z,k1.w};
            float vp[8] = {v0.x,v0.y,v0.z,v0.w,v1.x,v1.y,v1.z,v1.w};
            uint32_t pk[4], pv[4];
            #pragma unroll
            for (int j = 0; j < 4; ++j) {
                uint32_t lo = f2bf(phi_f(kp[2*j],   sreg[2*j],   breg[2*j]));
                uint32_t hi = f2bf(phi_f(kp[2*j+1], sreg[2*j+1], breg[2*j+1]));
                pk[j] = lo | (hi << 16);
                lo = f2bf(vp[2*j]); hi = f2bf(vp[2*j+1]);
                pv[j] = lo | (hi << 16);
            }
            *(uint4*)&pk_bf[sr*136 + sc] = *(uint4*)pk;
            *(uint4*)&v_bf [sr*136 + sc] = *(uint4*)pv;
        }
        __syncthreads();   // B1

        // ---- 2. LDS transpose -> pkT[d][r], vT[e][r]; Z partials
        {
            const int dp  = tid & 63;      // word pair: d0=2dp, d1=2dp+1
            const int seg = tid >> 6;      // 0..7 -> r0 = 4*seg
            const int r0  = seg * 4;
            uint32_t w0 = *(const uint32_t*)&pk_bf[(r0+0)*136 + 2*dp];
            uint32_t w1 = *(const uint32_t*)&pk_bf[(r0+1)*136 + 2*dp];
            uint32_t w2 = *(const uint32_t*)&pk_bf[(r0+2)*136 + 2*dp];
            uint32_t w3 = *(const uint32_t*)&pk_bf[(r0+3)*136 + 2*dp];
            uint2 lo, hi;
            lo.x = (w0 & 0xffffu) | (w1 << 16);
            lo.y = (w2 & 0xffffu) | (w3 << 16);
            hi.x = (w0 >> 16) | (w1 & 0xffff0000u);
            hi.y = (w2 >> 16) | (w3 & 0xffff0000u);
            *(uint2*)&pkT[(2*dp+0)*40 + r0] = lo;
            *(uint2*)&pkT[(2*dp+1)*40 + r0] = hi;
            Zpart[seg*128 + 2*dp+0] = bflo(w0)+bflo(w1)+bflo(w2)+bflo(w3);
            Zpart[seg*128 + 2*dp+1] = bfhi(w0)+bfhi(w1)+bfhi(w2)+bfhi(w3);
            w0 = *(const uint32_t*)&v_bf[(r0+0)*136 + 2*dp];
            w1 = *(const uint32_t*)&v_bf[(r0+1)*136 + 2*dp];
            w2 = *(const uint32_t*)&v_bf[(r0+2)*136 + 2*dp];
            w3 = *(const uint32_t*)&v_bf[(r0+3)*136 + 2*dp];
            lo.x = (w0 & 0xffffu) | (w1 << 16);
            lo.y = (w2 & 0xffffu) | (w3 << 16);
            hi.x = (w0 >> 16) | (w1 & 0xffff0000u);
            hi.y = (w2 >> 16) | (w3 & 0xffff0000u);
            *(uint2*)&vT[(2*dp+0)*40 + r0] = lo;
            *(uint2*)&vT[(2*dp+1)*40 + r0] = hi;
        }
        __syncthreads();   // B2

        // ---- 3. Z update + S-update MFMAs (S[d][e] += sum_r pk[r][d] v[r][e])
        if (tid < 128) {
            float z = Zl[tid];
            #pragma unroll
            for (int g = 0; g < 8; ++g) z += Zpart[g*128 + tid];
            Zl[tid] = z;
        }
        {
            bf16x8 bv = *(const bf16x8*)&vT[(16*wv + i15)*40 + 8*q4];
            #pragma unroll
            for (int mt = 0; mt < 8; ++mt) {
                bf16x8 av = *(const bf16x8*)&pkT[(16*mt + i15)*40 + 8*q4];
                accS[mt] = __builtin_amdgcn_mfma_f32_16x16x32_bf16(av, bv, accS[mt], 0, 0, 0);
            }
        }

        if (PHASE2) {
            __syncthreads();   // B3 (pkT reads done -> pq_bf may overwrite)

            // ---- 4. stage phi(Q) into pq_bf; emit S as bf16 (e-major) for num
            {
                const float4 a0 = *(const float4*)(Q + rowoff);
                const float4 a1 = *(const float4*)(Q + rowoff + 4);
                float qp[8] = {a0.x,a0.y,a0.z,a0.w,a1.x,a1.y,a1.z,a1.w};
                uint32_t pq[4];
                #pragma unroll
                for (int j = 0; j < 4; ++j) {
                    uint32_t lo = f2bf(phi_f(qp[2*j],   sreg[2*j],   breg[2*j]));
                    uint32_t hi = f2bf(phi_f(qp[2*j+1], sreg[2*j+1], breg[2*j+1]));
                    pq[j] = lo | (hi << 16);
                }
                *(uint4*)&pq_bf[sr*136 + sc] = *(uint4*)pq;
            }
            #pragma unroll
            for (int mt = 0; mt < 8; ++mt) {
                uint2 o;
                o.x = (uint32_t)f2bf(accS[mt][0]) | ((uint32_t)f2bf(accS[mt][1]) << 16);
                o.y = (uint32_t)f2bf(accS[mt][2]) | ((uint32_t)f2bf(accS[mt][3]) << 16);
                *(uint2*)&S_bfT[(16*wv + i15)*136 + 16*mt + 4*q4] = o;
            }
            __syncthreads();   // B4

            // ---- 5. num MFMAs + den partials
            f32x4 acc2[2];
            acc2[0] = (f32x4){0.f,0.f,0.f,0.f};
            acc2[1] = (f32x4){0.f,0.f,0.f,0.f};
            #pragma unroll
            for (int ks = 0; ks < 4; ++ks) {
                bf16x8 sb = *(const bf16x8*)&S_bfT[(16*wv + i15)*136 + 32*ks + 8*q4];
                #pragma unroll
                for (int qt = 0; qt < 2; ++qt) {
                    bf16x8 qa = *(const bf16x8*)&pq_bf[(16*qt + i15)*136 + 32*ks + 8*q4];
                    acc2[qt] = __builtin_amdgcn_mfma_f32_16x16x32_bf16(qa, sb, acc2[qt], 0, 0, 0);
                }
            }
            {
                const int dq = tid >> 4;      // q row 0..31
                const int pt = tid & 15;      // d segment [8pt, 8pt+8)
                float sden = 0.f;
                #pragma unroll
                for (int j = 0; j < 4; ++j) {
                    uint32_t w = *(const uint32_t*)&pq_bf[dq*136 + 8*pt + 2*j];
                    sden += bflo(w) * Zl[8*pt + 2*j] + bfhi(w) * Zl[8*pt + 2*j + 1];
                }
                den_part[dq*16 + pt] = sden;
            }
            __syncthreads();   // B5
            if (tid < 32) {
                float sden = 0.f;
                #pragma unroll
                for (int j = 0; j < 16; ++j) sden += den_part[tid*16 + j];
                inv_den[tid] = 1.0f / fmaxf(sden, 1e-6f);
            }
            __syncthreads();   // B6

            // ---- 7. out = num * inv_den
            #pragma unroll
            for (int qt = 0; qt < 2; ++qt) {
                #pragma unroll
                for (int r = 0; r < 4; ++r) {
                    int qrow = 16*qt + 4*q4 + r;
                    float o = acc2[qt][r] * inv_den[qrow];
                    out[base + (size_t)(blk*BS + qrow)*DDIM + 16*wv + i15] = o;
                }
            }
        }
    }

    if (!PHASE2) {
        #pragma unroll
        for (int mt = 0; mt < 8; ++mt) {
            #pragma unroll
            for (int r = 0; r < 4; ++r) {
                int d = 16*mt + 4*q4 + r;
                stbase[d*DDIM + 16*wv + i15] = accS[mt][r];
            }
        }
        if (tid < 128) stbase[DDIM*DDIM + tid] = Zl[tid];
    }
}

// In-place exclusive prefix over chunk states, per chain. grid 32*16, block 256.
__global__ void la_prefix(float* __restrict__ states) {
    const int bh = blockIdx.x >> 4;
    const int sl = blockIdx.x & 15;
    const int slice = STATE_SZ / 16;  // 1032
    float* p0 = states + (size_t)bh * CHUNKS * STATE_SZ + sl * slice;
    for (int i = threadIdx.x; i < slice; i += 256) {
        float run = 0.f;
        float* p = p0 + i;
        #pragma unroll
        for (int c = 0; c < CHUNKS; ++c) {
            float v = p[(size_t)c * STATE_SZ];
            p[(size_t)c * STATE_SZ] = run;
            run += v;
        }
    }
}

extern "C" void kernel_launch(void* const* d_in, const int* in_sizes, int n_in,
                              void* d_out, int out_size, void* d_ws, size_t ws_size,
                              hipStream_t stream) {
    const float* Q     = (const float*)d_in[0];
    const float* K     = (const float*)d_in[1];
    const float* V     = (const float*)d_in[2];
    const float* scale = (const float*)d_in[3];
    const float* bias  = (const float*)d_in[4];
    float* out    = (float*)d_out;
    float* states = (float*)d_ws;   // needs 32*16*16512*4 = 33.8 MB

    hipLaunchKernelGGL((la_phase<false>), dim3(BH*CHUNKS), dim3(512), SMEM_BYTES, stream,
                       Q, K, V, scale, bias, states, out);
    hipLaunchKernelGGL(la_prefix, dim3(BH*16), dim3(256), 0, stream, states);
    hipLaunchKernelGGL((la_phase<true>), dim3(BH*CHUNKS), dim3(512), SMEM_BYTES, stream,
                       Q, K, V, scale, bias, states, out);
}